// Round 4
// baseline (589.691 us; speedup 1.0000x reference)
//
#include <hip/hip_runtime.h>
#include <hip/hip_bf16.h>
#include <stdint.h>

#define N_TOK 8192
#define C_DIM 1024
#define H_DIM 4096
#define E_NUM 5
#define LN_EPS 1e-5f

typedef __hip_bfloat16 bf16;
using s8v = __attribute__((ext_vector_type(8))) short;
using f4v = __attribute__((ext_vector_type(4))) float;

// async global->LDS, 16B per lane. LDS dest must be linear: wave-uniform base + lane*16.
__device__ __forceinline__ void async_ld16(const bf16* g, bf16* l) {
    __builtin_amdgcn_global_load_lds(
        (const __attribute__((address_space(1))) void*)g,
        (__attribute__((address_space(3))) void*)l,
        16, 0, 0);
}

// meta layout (ints): [0..4]=counts, [5..10]=offsets(6), [11..15]=cursors
__global__ void init_meta_kernel(int* meta) {
    if (threadIdx.x < 16) meta[threadIdx.x] = 0;
}

__global__ __launch_bounds__(256) void count_kernel(
    const int* __restrict__ win, int* __restrict__ meta)
{
    int n = blockIdx.x * 256 + threadIdx.x;
    atomicAdd(&meta[win[n]], 1);
}

__global__ void scan_kernel(int* meta) {
    if (threadIdx.x == 0) {
        int off = 0;
        for (int e = 0; e < E_NUM; ++e) {
            meta[5 + e] = off;
            off += meta[e];
            meta[11 + e] = 0;
        }
        meta[5 + E_NUM] = off;
    }
}

__global__ __launch_bounds__(256) void scatter_kernel(
    const int* __restrict__ win, int* __restrict__ meta,
    int* __restrict__ idx, int* __restrict__ pos)
{
    int n = blockIdx.x * 256 + threadIdx.x;
    int e = win[n];
    int p = meta[5 + e] + atomicAdd(&meta[11 + e], 1);
    idx[p] = n;
    pos[n] = p;
}

// LN + confidence; writes hbuf and scale in expert-SORTED order (via pos[n]).
__global__ __launch_bounds__(256) void ln_conf_kernel(
    const float* __restrict__ x, const int* __restrict__ win,
    const float* __restrict__ gamma, const float* __restrict__ beta,
    const float* __restrict__ wc, const float* __restrict__ bc,
    const int* __restrict__ pos,
    bf16* __restrict__ hbuf, float* __restrict__ scl)
{
    int n = blockIdx.x;
    int t = threadIdx.x;
    const float* xr = x + (size_t)n * C_DIM;
    float v[4];
    float s = 0.f, ss = 0.f;
#pragma unroll
    for (int i = 0; i < 4; ++i) {
        v[i] = xr[t + i * 256];
        s += v[i];
        ss += v[i] * v[i];
    }
#pragma unroll
    for (int off = 32; off > 0; off >>= 1) {
        s  += __shfl_down(s, off);
        ss += __shfl_down(ss, off);
    }
    __shared__ float red[8];
    __shared__ float mu_s, rv_s;
    int wave = t >> 6, lane = t & 63;
    if (lane == 0) { red[wave] = s; red[4 + wave] = ss; }
    __syncthreads();
    if (t == 0) {
        float S  = red[0] + red[1] + red[2] + red[3];
        float SS = red[4] + red[5] + red[6] + red[7];
        float mu = S * (1.f / C_DIM);
        float var = SS * (1.f / C_DIM) - mu * mu;
        mu_s = mu;
        rv_s = rsqrtf(var + LN_EPS);
    }
    __syncthreads();
    float mu = mu_s, rv = rv_s;
    int e = win[n];
    int p = pos[n];
    const float* wce = wc + (size_t)e * C_DIM;
    float dot = 0.f;
#pragma unroll
    for (int i = 0; i < 4; ++i) {
        int ci = t + i * 256;
        float hv = (v[i] - mu) * rv * gamma[ci] + beta[ci];
        hbuf[(size_t)p * C_DIM + ci] = (bf16)hv;
        dot += hv * wce[ci];
    }
#pragma unroll
    for (int off = 32; off > 0; off >>= 1) dot += __shfl_down(dot, off);
    if (lane == 0) red[wave] = dot;
    __syncthreads();
    if (t == 0) {
        float z = red[0] + red[1] + red[2] + red[3] + bc[e];
        float conf = 1.f / (1.f + expf(-z));
        scl[p] = conf / (conf + 1e-6f);
    }
}

// src: [E][R][S] fp32 -> dst: [E][S][R] bf16.  64x64 tiles, float4 loads, 16B stores.
__global__ __launch_bounds__(256) void transpose_cvt_kernel(
    const float* __restrict__ src, bf16* __restrict__ dst, int R, int S)
{
    __shared__ float tile[64][65];
    size_t ebase = (size_t)blockIdx.z * (size_t)R * (size_t)S;
    int s0 = blockIdx.x * 64;
    int r0 = blockIdx.y * 64;
    int t = threadIdx.x;
    int lr = t >> 4;
    int lc = (t & 15) * 4;
#pragma unroll
    for (int i = 0; i < 4; ++i) {
        int r = lr + i * 16;
        float4 v = *(const float4*)(src + ebase + (size_t)(r0 + r) * S + s0 + lc);
        tile[r][lc + 0] = v.x;
        tile[r][lc + 1] = v.y;
        tile[r][lc + 2] = v.z;
        tile[r][lc + 3] = v.w;
    }
    __syncthreads();
    int sc = t >> 2;
#pragma unroll
    for (int p = 0; p < 2; ++p) {
        int ch = (t & 3) + p * 4;
        bf16 vals[8];
#pragma unroll
        for (int j = 0; j < 8; ++j)
            vals[j] = (bf16)tile[ch * 8 + j][sc];
        *(s8v*)(dst + ebase + (size_t)(s0 + sc) * R + r0 + ch * 8) = *(s8v*)vals;
    }
}

// ---------------- BK=64 GEMM cores ----------------
// LDS tile: [128 rows][64 K] bf16, stored as 8 chunks of 8 elements per row,
// chunk slot kc holds global chunk kc ^ (row&7)  (bank swizzle, load-side XOR).
// Staging: thread t, instr i in 0..3: slot = i*256+t -> row=(t>>3)+32*i, kc=t&7.
// global col chunk = kc ^ (row&7) = (t&7) ^ ((t>>3)&7)   (same for all i).

// Stage 1: ks[p][hcol] = relu(hbuf[p] @ W1t[e][hcol])^2  (sorted rows, bf16 out)
__global__ __launch_bounds__(256) void gemm1_kernel(
    const bf16* __restrict__ hbuf, const bf16* __restrict__ w1t,
    const int* __restrict__ meta, bf16* __restrict__ ks)
{
    int e = blockIdx.z;
    int base_p = meta[5 + e];
    int cnt = meta[6 + e] - base_p;
    int m0 = blockIdx.y * 128;
    if (m0 >= cnt) return;
    int n0 = blockIdx.x * 128;

    __shared__ __align__(16) bf16 As[128 * 64];
    __shared__ __align__(16) bf16 Bs[128 * 64];

    int t = threadIdx.x;
    int lane = t & 63;
    int wv = t >> 6;
    int wr = wv >> 1, wcol = wv & 1;

    int kc_sw = ((t & 7) ^ ((t >> 3) & 7)) * 8;   // global K-element offset of my chunk
    const bf16* ga[4];
    const bf16* gb[4];
    const bf16* wbase = w1t + (size_t)e * H_DIM * C_DIM;
#pragma unroll
    for (int i = 0; i < 4; ++i) {
        int row = (t >> 3) + 32 * i;
        int ra = min(m0 + row, cnt - 1);
        ga[i] = hbuf + (size_t)(base_p + ra) * C_DIM + kc_sw;
        gb[i] = wbase + (size_t)(n0 + row) * C_DIM + kc_sw;
    }

    int q = lane >> 4;
    int r7 = lane & 7;
    int arow = wr * 64 + (lane & 15);
    int brow = wcol * 64 + (lane & 15);
    int koff0 = ((q ^ r7) * 8);            // kk=0: chunk q
    int koff1 = (((4 + q) ^ r7) * 8);      // kk=1: chunk 4+q

    f4v acc[4][4];
    f4v zero = {0.f, 0.f, 0.f, 0.f};
#pragma unroll
    for (int i = 0; i < 4; ++i)
#pragma unroll
        for (int j = 0; j < 4; ++j) acc[i][j] = zero;

    for (int kb = 0; kb < C_DIM / 64; ++kb) {
        __syncthreads();
#pragma unroll
        for (int i = 0; i < 4; ++i) {
            async_ld16(ga[i], As + (i * 256 + t) * 8); ga[i] += 64;
            async_ld16(gb[i], Bs + (i * 256 + t) * 8); gb[i] += 64;
        }
        __syncthreads();
        s8v af[4], bfv[4];
#pragma unroll
        for (int mi = 0; mi < 4; ++mi)
            af[mi] = *(const s8v*)&As[(arow + mi * 16) * 64 + koff0];
#pragma unroll
        for (int ni = 0; ni < 4; ++ni)
            bfv[ni] = *(const s8v*)&Bs[(brow + ni * 16) * 64 + koff0];
#pragma unroll
        for (int mi = 0; mi < 4; ++mi)
#pragma unroll
            for (int ni = 0; ni < 4; ++ni)
                acc[mi][ni] = __builtin_amdgcn_mfma_f32_16x16x32_bf16(af[mi], bfv[ni], acc[mi][ni], 0, 0, 0);
#pragma unroll
        for (int mi = 0; mi < 4; ++mi)
            af[mi] = *(const s8v*)&As[(arow + mi * 16) * 64 + koff1];
#pragma unroll
        for (int ni = 0; ni < 4; ++ni)
            bfv[ni] = *(const s8v*)&Bs[(brow + ni * 16) * 64 + koff1];
#pragma unroll
        for (int mi = 0; mi < 4; ++mi)
#pragma unroll
            for (int ni = 0; ni < 4; ++ni)
                acc[mi][ni] = __builtin_amdgcn_mfma_f32_16x16x32_bf16(af[mi], bfv[ni], acc[mi][ni], 0, 0, 0);
    }

#pragma unroll
    for (int mi = 0; mi < 4; ++mi) {
#pragma unroll
        for (int r = 0; r < 4; ++r) {
            int row_local = wr * 64 + mi * 16 + ((lane >> 4) << 2) + r;
            int gm = m0 + row_local;
            if (gm < cnt) {
                size_t p = (size_t)(base_p + gm);
#pragma unroll
                for (int ni = 0; ni < 4; ++ni) {
                    int col = n0 + wcol * 64 + ni * 16 + (lane & 15);
                    float v = acc[mi][ni][r];
                    float rl = fmaxf(v, 0.f);
                    ks[p * H_DIM + col] = (bf16)(rl * rl);
                }
            }
        }
    }
}

// Stage 2: out[tok] = x[tok] + (ks[p] @ W2t[e][c])*scl[p]  (fused epilogue)
__global__ __launch_bounds__(256) void gemm2_kernel(
    const bf16* __restrict__ ks, const bf16* __restrict__ w2t,
    const int* __restrict__ idx, const int* __restrict__ meta,
    const float* __restrict__ x, const float* __restrict__ scl,
    float* __restrict__ out)
{
    int e = blockIdx.z;
    int base_p = meta[5 + e];
    int cnt = meta[6 + e] - base_p;
    int m0 = blockIdx.y * 128;
    if (m0 >= cnt) return;
    int n0 = blockIdx.x * 128;

    __shared__ __align__(16) bf16 As[128 * 64];
    __shared__ __align__(16) bf16 Bs[128 * 64];

    int t = threadIdx.x;
    int lane = t & 63;
    int wv = t >> 6;
    int wr = wv >> 1, wcol = wv & 1;

    int kc_sw = ((t & 7) ^ ((t >> 3) & 7)) * 8;
    const bf16* ga[4];
    const bf16* gb[4];
    const bf16* wbase = w2t + (size_t)e * C_DIM * H_DIM;
#pragma unroll
    for (int i = 0; i < 4; ++i) {
        int row = (t >> 3) + 32 * i;
        int ra = min(m0 + row, cnt - 1);
        ga[i] = ks + (size_t)(base_p + ra) * H_DIM + kc_sw;
        gb[i] = wbase + (size_t)(n0 + row) * H_DIM + kc_sw;
    }

    int q = lane >> 4;
    int r7 = lane & 7;
    int arow = wr * 64 + (lane & 15);
    int brow = wcol * 64 + (lane & 15);
    int koff0 = ((q ^ r7) * 8);
    int koff1 = (((4 + q) ^ r7) * 8);

    f4v acc[4][4];
    f4v zero = {0.f, 0.f, 0.f, 0.f};
#pragma unroll
    for (int i = 0; i < 4; ++i)
#pragma unroll
        for (int j = 0; j < 4; ++j) acc[i][j] = zero;

    for (int kb = 0; kb < H_DIM / 64; ++kb) {
        __syncthreads();
#pragma unroll
        for (int i = 0; i < 4; ++i) {
            async_ld16(ga[i], As + (i * 256 + t) * 8); ga[i] += 64;
            async_ld16(gb[i], Bs + (i * 256 + t) * 8); gb[i] += 64;
        }
        __syncthreads();
        s8v af[4], bfv[4];
#pragma unroll
        for (int mi = 0; mi < 4; ++mi)
            af[mi] = *(const s8v*)&As[(arow + mi * 16) * 64 + koff0];
#pragma unroll
        for (int ni = 0; ni < 4; ++ni)
            bfv[ni] = *(const s8v*)&Bs[(brow + ni * 16) * 64 + koff0];
#pragma unroll
        for (int mi = 0; mi < 4; ++mi)
#pragma unroll
            for (int ni = 0; ni < 4; ++ni)
                acc[mi][ni] = __builtin_amdgcn_mfma_f32_16x16x32_bf16(af[mi], bfv[ni], acc[mi][ni], 0, 0, 0);
#pragma unroll
        for (int mi = 0; mi < 4; ++mi)
            af[mi] = *(const s8v*)&As[(arow + mi * 16) * 64 + koff1];
#pragma unroll
        for (int ni = 0; ni < 4; ++ni)
            bfv[ni] = *(const s8v*)&Bs[(brow + ni * 16) * 64 + koff1];
#pragma unroll
        for (int mi = 0; mi < 4; ++mi)
#pragma unroll
            for (int ni = 0; ni < 4; ++ni)
                acc[mi][ni] = __builtin_amdgcn_mfma_f32_16x16x32_bf16(af[mi], bfv[ni], acc[mi][ni], 0, 0, 0);
    }

#pragma unroll
    for (int mi = 0; mi < 4; ++mi) {
        int tok[4];
        float sclv[4];
#pragma unroll
        for (int r = 0; r < 4; ++r) {
            int row_local = wr * 64 + mi * 16 + ((lane >> 4) << 2) + r;
            int gm = m0 + row_local;
            if (gm < cnt) {
                tok[r] = idx[base_p + gm];
                sclv[r] = scl[base_p + gm];
            } else {
                tok[r] = -1;
                sclv[r] = 0.f;
            }
        }
#pragma unroll
        for (int ni = 0; ni < 4; ++ni) {
            int col = n0 + wcol * 64 + ni * 16 + (lane & 15);
#pragma unroll
            for (int r = 0; r < 4; ++r) {
                if (tok[r] >= 0) {
                    size_t o = (size_t)tok[r] * C_DIM + col;
                    out[o] = x[o] + acc[mi][ni][r] * sclv[r];
                }
            }
        }
    }
}

extern "C" void kernel_launch(void* const* d_in, const int* in_sizes, int n_in,
                              void* d_out, int out_size, void* d_ws, size_t ws_size,
                              hipStream_t stream) {
    const float* x     = (const float*)d_in[0];
    const int*   win   = (const int*)d_in[1];
    const float* gamma = (const float*)d_in[2];
    const float* beta  = (const float*)d_in[3];
    const float* w1    = (const float*)d_in[4];
    const float* w2    = (const float*)d_in[5];
    const float* wc    = (const float*)d_in[6];
    const float* bc    = (const float*)d_in[7];
    float* out = (float*)d_out;

    char* ws = (char*)d_ws;
    size_t o = 0;
    bf16* w1t  = (bf16*)(ws + o); o += (size_t)E_NUM * H_DIM * C_DIM * 2;  // 40 MB
    bf16* w2t  = (bf16*)(ws + o); o += (size_t)E_NUM * C_DIM * H_DIM * 2;  // 40 MB
    bf16* hbuf = (bf16*)(ws + o); o += (size_t)N_TOK * C_DIM * 2;          // 16 MB
    bf16* ks   = (bf16*)(ws + o); o += (size_t)N_TOK * H_DIM * 2;          // 64 MB
    float* scl = (float*)(ws + o); o += (size_t)N_TOK * 4;
    int* idx   = (int*)(ws + o);   o += (size_t)N_TOK * 4;
    int* pos   = (int*)(ws + o);   o += (size_t)N_TOK * 4;
    int* meta  = (int*)(ws + o);   o += 64;

    hipLaunchKernelGGL(init_meta_kernel, dim3(1), dim3(64), 0, stream, meta);
    hipLaunchKernelGGL(count_kernel, dim3(N_TOK / 256), dim3(256), 0, stream, win, meta);
    hipLaunchKernelGGL(scan_kernel, dim3(1), dim3(64), 0, stream, meta);
    hipLaunchKernelGGL(scatter_kernel, dim3(N_TOK / 256), dim3(256), 0, stream, win, meta, idx, pos);
    hipLaunchKernelGGL(transpose_cvt_kernel, dim3(H_DIM / 64, C_DIM / 64, E_NUM), dim3(256), 0, stream,
                       w1, w1t, C_DIM, H_DIM);
    hipLaunchKernelGGL(transpose_cvt_kernel, dim3(C_DIM / 64, H_DIM / 64, E_NUM), dim3(256), 0, stream,
                       w2, w2t, H_DIM, C_DIM);
    hipLaunchKernelGGL(ln_conf_kernel, dim3(N_TOK), dim3(256), 0, stream,
                       x, win, gamma, beta, wc, bc, pos, hbuf, scl);
    hipLaunchKernelGGL(gemm1_kernel, dim3(H_DIM / 128, 64, E_NUM), dim3(256), 0, stream,
                       hbuf, w1t, meta, ks);
    hipLaunchKernelGGL(gemm2_kernel, dim3(C_DIM / 128, 64, E_NUM), dim3(256), 0, stream,
                       ks, w2t, idx, meta, x, scl, out);
}

// Round 5
// 473.050 us; speedup vs baseline: 1.2466x; 1.2466x over previous
//
#include <hip/hip_runtime.h>
#include <hip/hip_bf16.h>
#include <stdint.h>

#define N_TOK 8192
#define C_DIM 1024
#define H_DIM 4096
#define E_NUM 5
#define LN_EPS 1e-5f

typedef __hip_bfloat16 bf16;
using s8v = __attribute__((ext_vector_type(8))) short;
using f4v = __attribute__((ext_vector_type(4))) float;

// async global->LDS, 16B per lane. LDS dest must be linear: wave-uniform base + lane*16.
__device__ __forceinline__ void async_ld16(const bf16* g, bf16* l) {
    __builtin_amdgcn_global_load_lds(
        (const __attribute__((address_space(1))) void*)g,
        (__attribute__((address_space(3))) void*)l,
        16, 0, 0);
}

// meta layout (ints): [0..4]=counts, [5..10]=offsets(6), [11..15]=cursors
__global__ void init_meta_kernel(int* meta) {
    if (threadIdx.x < 16) meta[threadIdx.x] = 0;
}

// Hierarchical count: LDS counters per block, then E_NUM global atomics/block.
__global__ __launch_bounds__(256) void count_kernel(
    const int* __restrict__ win, int* __restrict__ meta)
{
    __shared__ int c[E_NUM];
    if (threadIdx.x < E_NUM) c[threadIdx.x] = 0;
    __syncthreads();
    int n = blockIdx.x * 256 + threadIdx.x;
    atomicAdd(&c[win[n]], 1);          // LDS atomic (block-local contention only)
    __syncthreads();
    if (threadIdx.x < E_NUM) atomicAdd(&meta[threadIdx.x], c[threadIdx.x]);
}

__global__ void scan_kernel(int* meta) {
    if (threadIdx.x == 0) {
        int off = 0;
        for (int e = 0; e < E_NUM; ++e) {
            meta[5 + e] = off;
            off += meta[e];
            meta[11 + e] = 0;
        }
        meta[5 + E_NUM] = off;
    }
}

// Hierarchical scatter: local rank via LDS atomics, one range-reservation
// global atomic per expert per block. Position order within an expert is
// nondeterministic across blocks, but output is permutation-invariant.
__global__ __launch_bounds__(256) void scatter_kernel(
    const int* __restrict__ win, int* __restrict__ meta,
    int* __restrict__ idx, int* __restrict__ pos)
{
    __shared__ int c[E_NUM];
    __shared__ int base[E_NUM];
    if (threadIdx.x < E_NUM) c[threadIdx.x] = 0;
    __syncthreads();
    int n = blockIdx.x * 256 + threadIdx.x;
    int e = win[n];
    int lr = atomicAdd(&c[e], 1);      // LDS atomic -> local rank
    __syncthreads();
    if (threadIdx.x < E_NUM)
        base[threadIdx.x] = atomicAdd(&meta[11 + threadIdx.x], c[threadIdx.x]);
    __syncthreads();
    int p = meta[5 + e] + base[e] + lr;
    idx[p] = n;
    pos[n] = p;
}

// LN + confidence; writes hbuf and scale in expert-SORTED order (via pos[n]).
__global__ __launch_bounds__(256) void ln_conf_kernel(
    const float* __restrict__ x, const int* __restrict__ win,
    const float* __restrict__ gamma, const float* __restrict__ beta,
    const float* __restrict__ wc, const float* __restrict__ bc,
    const int* __restrict__ pos,
    bf16* __restrict__ hbuf, float* __restrict__ scl)
{
    int n = blockIdx.x;
    int t = threadIdx.x;
    const float* xr = x + (size_t)n * C_DIM;
    float v[4];
    float s = 0.f, ss = 0.f;
#pragma unroll
    for (int i = 0; i < 4; ++i) {
        v[i] = xr[t + i * 256];
        s += v[i];
        ss += v[i] * v[i];
    }
#pragma unroll
    for (int off = 32; off > 0; off >>= 1) {
        s  += __shfl_down(s, off);
        ss += __shfl_down(ss, off);
    }
    __shared__ float red[8];
    __shared__ float mu_s, rv_s;
    int wave = t >> 6, lane = t & 63;
    if (lane == 0) { red[wave] = s; red[4 + wave] = ss; }
    __syncthreads();
    if (t == 0) {
        float S  = red[0] + red[1] + red[2] + red[3];
        float SS = red[4] + red[5] + red[6] + red[7];
        float mu = S * (1.f / C_DIM);
        float var = SS * (1.f / C_DIM) - mu * mu;
        mu_s = mu;
        rv_s = rsqrtf(var + LN_EPS);
    }
    __syncthreads();
    float mu = mu_s, rv = rv_s;
    int e = win[n];
    int p = pos[n];
    const float* wce = wc + (size_t)e * C_DIM;
    float dot = 0.f;
#pragma unroll
    for (int i = 0; i < 4; ++i) {
        int ci = t + i * 256;
        float hv = (v[i] - mu) * rv * gamma[ci] + beta[ci];
        hbuf[(size_t)p * C_DIM + ci] = (bf16)hv;
        dot += hv * wce[ci];
    }
#pragma unroll
    for (int off = 32; off > 0; off >>= 1) dot += __shfl_down(dot, off);
    if (lane == 0) red[wave] = dot;
    __syncthreads();
    if (t == 0) {
        float z = red[0] + red[1] + red[2] + red[3] + bc[e];
        float conf = 1.f / (1.f + expf(-z));
        scl[p] = conf / (conf + 1e-6f);
    }
}

// src: [E][R][S] fp32 -> dst: [E][S][R] bf16.  64x64 tiles, float4 loads, 16B stores.
__global__ __launch_bounds__(256) void transpose_cvt_kernel(
    const float* __restrict__ src, bf16* __restrict__ dst, int R, int S)
{
    __shared__ float tile[64][65];
    size_t ebase = (size_t)blockIdx.z * (size_t)R * (size_t)S;
    int s0 = blockIdx.x * 64;
    int r0 = blockIdx.y * 64;
    int t = threadIdx.x;
    int lr = t >> 4;
    int lc = (t & 15) * 4;
#pragma unroll
    for (int i = 0; i < 4; ++i) {
        int r = lr + i * 16;
        float4 v = *(const float4*)(src + ebase + (size_t)(r0 + r) * S + s0 + lc);
        tile[r][lc + 0] = v.x;
        tile[r][lc + 1] = v.y;
        tile[r][lc + 2] = v.z;
        tile[r][lc + 3] = v.w;
    }
    __syncthreads();
    int sc = t >> 2;
#pragma unroll
    for (int p = 0; p < 2; ++p) {
        int ch = (t & 3) + p * 4;
        bf16 vals[8];
#pragma unroll
        for (int j = 0; j < 8; ++j)
            vals[j] = (bf16)tile[ch * 8 + j][sc];
        *(s8v*)(dst + ebase + (size_t)(s0 + sc) * R + r0 + ch * 8) = *(s8v*)vals;
    }
}

// ---------------- BK=32 GEMM cores (proven R2/R3 structure) ----------------

// Stage 1: ks[p][hcol] = relu(hbuf[p] @ W1t[e][hcol])^2  (sorted rows, bf16 out)
__global__ __launch_bounds__(256) void gemm1_kernel(
    const bf16* __restrict__ hbuf, const bf16* __restrict__ w1t,
    const int* __restrict__ meta, bf16* __restrict__ ks)
{
    int e = blockIdx.z;
    int base_p = meta[5 + e];
    int cnt = meta[6 + e] - base_p;
    int m0 = blockIdx.y * 128;
    if (m0 >= cnt) return;
    int n0 = blockIdx.x * 128;

    __shared__ __align__(16) bf16 As[128 * 32];
    __shared__ __align__(16) bf16 Bs[128 * 32];

    int t = threadIdx.x;
    int lane = t & 63;
    int wv = t >> 6;
    int wr = wv >> 1, wcol = wv & 1;

    int rowA = t >> 2;
    int kcol = (((t & 3) ^ (rowA & 3)) * 8);    // XOR-swizzled K-chunk

    int r1 = min(m0 + rowA, cnt - 1);
    int r2 = min(m0 + 64 + rowA, cnt - 1);
    const bf16* ga1 = hbuf + (size_t)(base_p + r1) * C_DIM + kcol;
    const bf16* ga2 = hbuf + (size_t)(base_p + r2) * C_DIM + kcol;
    const bf16* wbase = w1t + (size_t)e * H_DIM * C_DIM;
    const bf16* gb1 = wbase + (size_t)(n0 + rowA) * C_DIM + kcol;
    const bf16* gb2 = wbase + (size_t)(n0 + 64 + rowA) * C_DIM + kcol;

    bf16* la1 = As + t * 8;
    bf16* la2 = As + 2048 + t * 8;
    bf16* lb1 = Bs + t * 8;
    bf16* lb2 = Bs + 2048 + t * 8;

    int koff = (((lane >> 4) ^ (lane & 3)) * 8);
    int arow = wr * 64 + (lane & 15);
    int brow = wcol * 64 + (lane & 15);

    f4v acc[4][4];
    f4v zero = {0.f, 0.f, 0.f, 0.f};
#pragma unroll
    for (int i = 0; i < 4; ++i)
#pragma unroll
        for (int j = 0; j < 4; ++j) acc[i][j] = zero;

    for (int kb = 0; kb < C_DIM / 32; ++kb) {
        __syncthreads();
        async_ld16(ga1, la1); ga1 += 32;
        async_ld16(ga2, la2); ga2 += 32;
        async_ld16(gb1, lb1); gb1 += 32;
        async_ld16(gb2, lb2); gb2 += 32;
        __syncthreads();
        s8v af[4], bfv[4];
#pragma unroll
        for (int mi = 0; mi < 4; ++mi)
            af[mi] = *(const s8v*)&As[(arow + mi * 16) * 32 + koff];
#pragma unroll
        for (int ni = 0; ni < 4; ++ni)
            bfv[ni] = *(const s8v*)&Bs[(brow + ni * 16) * 32 + koff];
#pragma unroll
        for (int mi = 0; mi < 4; ++mi)
#pragma unroll
            for (int ni = 0; ni < 4; ++ni)
                acc[mi][ni] = __builtin_amdgcn_mfma_f32_16x16x32_bf16(af[mi], bfv[ni], acc[mi][ni], 0, 0, 0);
    }

#pragma unroll
    for (int mi = 0; mi < 4; ++mi) {
#pragma unroll
        for (int r = 0; r < 4; ++r) {
            int row_local = wr * 64 + mi * 16 + ((lane >> 4) << 2) + r;
            int gm = m0 + row_local;
            if (gm < cnt) {
                size_t p = (size_t)(base_p + gm);
#pragma unroll
                for (int ni = 0; ni < 4; ++ni) {
                    int col = n0 + wcol * 64 + ni * 16 + (lane & 15);
                    float v = acc[mi][ni][r];
                    float rl = fmaxf(v, 0.f);
                    ks[p * H_DIM + col] = (bf16)(rl * rl);
                }
            }
        }
    }
}

// Stage 2: out[tok] = x[tok] + (ks[p] @ W2t[e][c])*scl[p]  (fused epilogue)
__global__ __launch_bounds__(256) void gemm2_kernel(
    const bf16* __restrict__ ks, const bf16* __restrict__ w2t,
    const int* __restrict__ idx, const int* __restrict__ meta,
    const float* __restrict__ x, const float* __restrict__ scl,
    float* __restrict__ out)
{
    int e = blockIdx.z;
    int base_p = meta[5 + e];
    int cnt = meta[6 + e] - base_p;
    int m0 = blockIdx.y * 128;
    if (m0 >= cnt) return;
    int n0 = blockIdx.x * 128;

    __shared__ __align__(16) bf16 As[128 * 32];
    __shared__ __align__(16) bf16 Bs[128 * 32];

    int t = threadIdx.x;
    int lane = t & 63;
    int wv = t >> 6;
    int wr = wv >> 1, wcol = wv & 1;

    int rowA = t >> 2;
    int kcol = (((t & 3) ^ (rowA & 3)) * 8);

    int r1 = min(m0 + rowA, cnt - 1);
    int r2 = min(m0 + 64 + rowA, cnt - 1);
    const bf16* ga1 = ks + (size_t)(base_p + r1) * H_DIM + kcol;
    const bf16* ga2 = ks + (size_t)(base_p + r2) * H_DIM + kcol;
    const bf16* wbase = w2t + (size_t)e * C_DIM * H_DIM;
    const bf16* gb1 = wbase + (size_t)(n0 + rowA) * H_DIM + kcol;
    const bf16* gb2 = wbase + (size_t)(n0 + 64 + rowA) * H_DIM + kcol;

    bf16* la1 = As + t * 8;
    bf16* la2 = As + 2048 + t * 8;
    bf16* lb1 = Bs + t * 8;
    bf16* lb2 = Bs + 2048 + t * 8;

    int koff = (((lane >> 4) ^ (lane & 3)) * 8);
    int arow = wr * 64 + (lane & 15);
    int brow = wcol * 64 + (lane & 15);

    f4v acc[4][4];
    f4v zero = {0.f, 0.f, 0.f, 0.f};
#pragma unroll
    for (int i = 0; i < 4; ++i)
#pragma unroll
        for (int j = 0; j < 4; ++j) acc[i][j] = zero;

    for (int kb = 0; kb < H_DIM / 32; ++kb) {
        __syncthreads();
        async_ld16(ga1, la1); ga1 += 32;
        async_ld16(ga2, la2); ga2 += 32;
        async_ld16(gb1, lb1); gb1 += 32;
        async_ld16(gb2, lb2); gb2 += 32;
        __syncthreads();
        s8v af[4], bfv[4];
#pragma unroll
        for (int mi = 0; mi < 4; ++mi)
            af[mi] = *(const s8v*)&As[(arow + mi * 16) * 32 + koff];
#pragma unroll
        for (int ni = 0; ni < 4; ++ni)
            bfv[ni] = *(const s8v*)&Bs[(brow + ni * 16) * 32 + koff];
#pragma unroll
        for (int mi = 0; mi < 4; ++mi)
#pragma unroll
            for (int ni = 0; ni < 4; ++ni)
                acc[mi][ni] = __builtin_amdgcn_mfma_f32_16x16x32_bf16(af[mi], bfv[ni], acc[mi][ni], 0, 0, 0);
    }

#pragma unroll
    for (int mi = 0; mi < 4; ++mi) {
        int tok[4];
        float sclv[4];
#pragma unroll
        for (int r = 0; r < 4; ++r) {
            int row_local = wr * 64 + mi * 16 + ((lane >> 4) << 2) + r;
            int gm = m0 + row_local;
            if (gm < cnt) {
                tok[r] = idx[base_p + gm];
                sclv[r] = scl[base_p + gm];
            } else {
                tok[r] = -1;
                sclv[r] = 0.f;
            }
        }
#pragma unroll
        for (int ni = 0; ni < 4; ++ni) {
            int col = n0 + wcol * 64 + ni * 16 + (lane & 15);
#pragma unroll
            for (int r = 0; r < 4; ++r) {
                if (tok[r] >= 0) {
                    size_t o = (size_t)tok[r] * C_DIM + col;
                    out[o] = x[o] + acc[mi][ni][r] * sclv[r];
                }
            }
        }
    }
}

extern "C" void kernel_launch(void* const* d_in, const int* in_sizes, int n_in,
                              void* d_out, int out_size, void* d_ws, size_t ws_size,
                              hipStream_t stream) {
    const float* x     = (const float*)d_in[0];
    const int*   win   = (const int*)d_in[1];
    const float* gamma = (const float*)d_in[2];
    const float* beta  = (const float*)d_in[3];
    const float* w1    = (const float*)d_in[4];
    const float* w2    = (const float*)d_in[5];
    const float* wc    = (const float*)d_in[6];
    const float* bc    = (const float*)d_in[7];
    float* out = (float*)d_out;

    char* ws = (char*)d_ws;
    size_t o = 0;
    bf16* w1t  = (bf16*)(ws + o); o += (size_t)E_NUM * H_DIM * C_DIM * 2;  // 40 MB
    bf16* w2t  = (bf16*)(ws + o); o += (size_t)E_NUM * C_DIM * H_DIM * 2;  // 40 MB
    bf16* hbuf = (bf16*)(ws + o); o += (size_t)N_TOK * C_DIM * 2;          // 16 MB
    bf16* ks   = (bf16*)(ws + o); o += (size_t)N_TOK * H_DIM * 2;          // 64 MB
    float* scl = (float*)(ws + o); o += (size_t)N_TOK * 4;
    int* idx   = (int*)(ws + o);   o += (size_t)N_TOK * 4;
    int* pos   = (int*)(ws + o);   o += (size_t)N_TOK * 4;
    int* meta  = (int*)(ws + o);   o += 64;

    hipLaunchKernelGGL(init_meta_kernel, dim3(1), dim3(64), 0, stream, meta);
    hipLaunchKernelGGL(count_kernel, dim3(N_TOK / 256), dim3(256), 0, stream, win, meta);
    hipLaunchKernelGGL(scan_kernel, dim3(1), dim3(64), 0, stream, meta);
    hipLaunchKernelGGL(scatter_kernel, dim3(N_TOK / 256), dim3(256), 0, stream, win, meta, idx, pos);
    hipLaunchKernelGGL(transpose_cvt_kernel, dim3(H_DIM / 64, C_DIM / 64, E_NUM), dim3(256), 0, stream,
                       w1, w1t, C_DIM, H_DIM);
    hipLaunchKernelGGL(transpose_cvt_kernel, dim3(C_DIM / 64, H_DIM / 64, E_NUM), dim3(256), 0, stream,
                       w2, w2t, H_DIM, C_DIM);
    hipLaunchKernelGGL(ln_conf_kernel, dim3(N_TOK), dim3(256), 0, stream,
                       x, win, gamma, beta, wc, bc, pos, hbuf, scl);
    hipLaunchKernelGGL(gemm1_kernel, dim3(H_DIM / 128, 64, E_NUM), dim3(256), 0, stream,
                       hbuf, w1t, meta, ks);
    hipLaunchKernelGGL(gemm2_kernel, dim3(C_DIM / 128, 64, E_NUM), dim3(256), 0, stream,
                       ks, w2t, idx, meta, x, scl, out);
}